// Round 1
// baseline (2570.238 us; speedup 1.0000x reference)
//
#include <hip/hip_runtime.h>
#include <math.h>

// Capsule dynamic routing, B=64, R=4608, C=32, Din=Dout=16, 3 iters.
// Key identities used:
//   b_ij after k iters = u_hat . (v_1 + ... + v_k)   (b starts at 0)
//   so we keep only vsum[B,C,16] and recompute couplings per pass.
//   u_hat is recomputed per pass (never materialized).

#define B_    64
#define R_    4608
#define C_    32
#define DIN   16
#define DOUT  16
#define RB    36            // r's per block
#define RCHUNKS (R_ / RB)   // 128

// Pass kernel. Grid: (RCHUNKS, 2 b-groups). Block: 512 = 32 c x 16 blocal.
// Thread (blocal, c) handles b = g*32+blocal and b+16 for RB consecutive r's.
// Softmax over C=32 is a pure wave shuffle (c == lane%32).
template<bool FIRST>
__global__ __launch_bounds__(512)
void caps_pass(const float* __restrict__ x, const float* __restrict__ W,
               const float* __restrict__ vsum, float* __restrict__ s_out)
{
    const int c  = threadIdx.x & 31;
    const int bl = threadIdx.x >> 5;          // 0..15
    const int g  = blockIdx.y;                // 0..1
    const int r0 = blockIdx.x * RB;
    const int b0 = g * 32 + bl;               // covers b0 and b0+16

    float sacc[2][DOUT];
#pragma unroll
    for (int h = 0; h < 2; ++h)
#pragma unroll
        for (int d = 0; d < DOUT; ++d) sacc[h][d] = 0.0f;

    float vreg[2][DOUT];
    if (!FIRST) {
#pragma unroll
        for (int h = 0; h < 2; ++h) {
            const float4* vp = (const float4*)(vsum + ((size_t)((b0 + 16*h) * C_ + c)) * DOUT);
            float4 a = vp[0], b = vp[1], cc = vp[2], dd = vp[3];
            vreg[h][0]=a.x;  vreg[h][1]=a.y;  vreg[h][2]=a.z;  vreg[h][3]=a.w;
            vreg[h][4]=b.x;  vreg[h][5]=b.y;  vreg[h][6]=b.z;  vreg[h][7]=b.w;
            vreg[h][8]=cc.x; vreg[h][9]=cc.y; vreg[h][10]=cc.z; vreg[h][11]=cc.w;
            vreg[h][12]=dd.x; vreg[h][13]=dd.y; vreg[h][14]=dd.z; vreg[h][15]=dd.w;
        }
    }

    for (int r = r0; r < r0 + RB; ++r) {
        const float4* wp = (const float4*)(W + ((size_t)(r * C_ + c)) * (DIN * DOUT));
#pragma unroll
        for (int h = 0; h < 2; ++h) {
            const int b = b0 + 16 * h;

            // load x[b, r, 0..15]
            float xr[DIN];
            {
                const float4* xp = (const float4*)(x + ((size_t)b * R_ + r) * DIN);
                float4 a = xp[0], bb = xp[1], cc = xp[2], dd = xp[3];
                xr[0]=a.x;  xr[1]=a.y;  xr[2]=a.z;  xr[3]=a.w;
                xr[4]=bb.x; xr[5]=bb.y; xr[6]=bb.z; xr[7]=bb.w;
                xr[8]=cc.x; xr[9]=cc.y; xr[10]=cc.z; xr[11]=cc.w;
                xr[12]=dd.x; xr[13]=dd.y; xr[14]=dd.z; xr[15]=dd.w;
            }

            // u[d] = sum_i x[i] * W[r,c,i,d]
            float u[DOUT];
#pragma unroll
            for (int d = 0; d < DOUT; ++d) u[d] = 0.0f;
#pragma unroll
            for (int i = 0; i < DIN; ++i) {
                const float xi = xr[i];
                float4 w0 = wp[i*4+0];
                float4 w1 = wp[i*4+1];
                float4 w2 = wp[i*4+2];
                float4 w3 = wp[i*4+3];
                u[0]  = fmaf(xi, w0.x, u[0]);
                u[1]  = fmaf(xi, w0.y, u[1]);
                u[2]  = fmaf(xi, w0.z, u[2]);
                u[3]  = fmaf(xi, w0.w, u[3]);
                u[4]  = fmaf(xi, w1.x, u[4]);
                u[5]  = fmaf(xi, w1.y, u[5]);
                u[6]  = fmaf(xi, w1.z, u[6]);
                u[7]  = fmaf(xi, w1.w, u[7]);
                u[8]  = fmaf(xi, w2.x, u[8]);
                u[9]  = fmaf(xi, w2.y, u[9]);
                u[10] = fmaf(xi, w2.z, u[10]);
                u[11] = fmaf(xi, w2.w, u[11]);
                u[12] = fmaf(xi, w3.x, u[12]);
                u[13] = fmaf(xi, w3.y, u[13]);
                u[14] = fmaf(xi, w3.z, u[14]);
                u[15] = fmaf(xi, w3.w, u[15]);
            }

            float cij;
            if (FIRST) {
                cij = 1.0f / C_;   // softmax of zeros
            } else {
                // logit t = u . vsum[b,c,:]
                float t = 0.0f;
#pragma unroll
                for (int d = 0; d < DOUT; ++d) t = fmaf(u[d], vreg[h][d], t);
                // softmax over c (32 lanes of the wave, lane = c + 32*parity)
                float m = t;
#pragma unroll
                for (int off = 16; off >= 1; off >>= 1)
                    m = fmaxf(m, __shfl_xor(m, off));
                const float e = __expf(t - m);
                float ssum = e;
#pragma unroll
                for (int off = 16; off >= 1; off >>= 1)
                    ssum += __shfl_xor(ssum, off);
                cij = e / ssum;
            }

#pragma unroll
            for (int d = 0; d < DOUT; ++d)
                sacc[h][d] = fmaf(cij, u[d], sacc[h][d]);
        }
    }

#pragma unroll
    for (int h = 0; h < 2; ++h) {
        float* sp = s_out + ((size_t)((b0 + 16*h) * C_ + c)) * DOUT;
#pragma unroll
        for (int d = 0; d < DOUT; ++d)
            atomicAdd(sp + d, sacc[h][d]);
    }
}

// squash(s) over the last dim (16). 32768 elements, 16-lane groups share (b,c).
__global__ __launch_bounds__(256)
void caps_squash(const float* __restrict__ s, float* __restrict__ vout,
                 float* __restrict__ vsum)
{
    const int idx = blockIdx.x * 256 + threadIdx.x;   // < 32768
    const float sv = s[idx];
    float sq = sv * sv;
#pragma unroll
    for (int off = 8; off >= 1; off >>= 1)
        sq += __shfl_xor(sq, off);
    const float n = sqrtf(sq);
    const float scale = sq / (1.0f + sq);
    const float v = scale * sv / (n + 1e-8f);
    if (vout) vout[idx] = v;
    if (vsum) vsum[idx] += v;
}

extern "C" void kernel_launch(void* const* d_in, const int* in_sizes, int n_in,
                              void* d_out, int out_size, void* d_ws, size_t ws_size,
                              hipStream_t stream)
{
    const float* x = (const float*)d_in[0];          // [64, 4608, 16]
    const float* W = (const float*)d_in[1];          // [4608, 32, 16, 16]
    float* out  = (float*)d_out;                     // [64, 32, 16]
    float* s    = (float*)d_ws;                      // 32768 f32
    float* vsum = s + 32768;                         // 32768 f32

    const dim3 grid(RCHUNKS, 2), blk(512);

    // zero s and vsum (contiguous)
    hipMemsetAsync(s, 0, 2 * 32768 * sizeof(float), stream);

    // iter 1: uniform coupling 1/32
    caps_pass<true><<<grid, blk, 0, stream>>>(x, W, nullptr, s);
    caps_squash<<<128, 256, 0, stream>>>(s, nullptr, vsum);   // vsum += v1

    // iter 2: coupling = softmax(u . v1)
    hipMemsetAsync(s, 0, 32768 * sizeof(float), stream);
    caps_pass<false><<<grid, blk, 0, stream>>>(x, W, vsum, s);
    caps_squash<<<128, 256, 0, stream>>>(s, nullptr, vsum);   // vsum += v2

    // iter 3: coupling = softmax(u . (v1+v2))
    hipMemsetAsync(s, 0, 32768 * sizeof(float), stream);
    caps_pass<false><<<grid, blk, 0, stream>>>(x, W, vsum, s);
    caps_squash<<<128, 256, 0, stream>>>(s, out, nullptr);    // out = v3
}

// Round 2
// 383.376 us; speedup vs baseline: 6.7042x; 6.7042x over previous
//
#include <hip/hip_runtime.h>
#include <math.h>

// Capsule dynamic routing, B=64, R=4608, C=32, Din=Dout=16, 3 iters.
// b-logits are linear in v: b after k iters = u_hat . (v1+...+vk), so we keep
// only vsum[B,C,16] and recompute u_hat per pass (never materialized).
//
// Pass kernel: 256 blocks (1/CU) x 1024 threads (16 waves).
// Thread (c = tid&31, dh = (tid>>5)&1, w = tid>>6) owns output tile
// [4 b = 4w..4w+3][c][8 d = dh*8..dh*8+7]. W[r] (32 KB) staged to LDS via
// global_load_lds (double-buffered, counted vmcnt), XOR-swizzled so the
// stride-1KB ds_read_b128 fan-out over c is 4-way instead of 16-way banked.
// x rows are wave-uniform -> scalar loads. Per-block partial sums written
// non-atomically to ws; tiny tree-reduce + squash kernels between passes.

#define B_    64
#define R_    4608
#define C_    32
#define RB    18
#define NBLK  (R_ / RB)      // 256
#define SELEM 32768          // B_*C_*16

__device__ __forceinline__ void gload_lds16(const void* g, void* l) {
    __builtin_amdgcn_global_load_lds(
        (const __attribute__((address_space(1))) void*)g,
        (__attribute__((address_space(3))) void*)l, 16, 0, 0);
}

template<bool FIRST, bool ATOMIC>
__global__ __launch_bounds__(1024, 4)
void caps_pass(const float* __restrict__ x, const float* __restrict__ W,
               const float* __restrict__ vsumg, float* __restrict__ sdst)
{
    __shared__ float wlds[2][8192];          // 2 x 32 KB W tiles
    const int tid  = threadIdx.x;
    const int lane = tid & 63;
    const int c    = tid & 31;
    const int dh   = (tid >> 5) & 1;
    const int w    = tid >> 6;               // wave 0..15
    const int r0   = blockIdx.x * RB;
    const int b0   = w << 2;                 // 4 b per wave

    // byte-level XOR swizzle key for this thread's W reads
    const int key = (c & 7) << 4;
    const int cb  = (c << 10) + (dh << 5);   // byte base within W tile (i=0,j=0)

    float sacc[4][8];
#pragma unroll
    for (int q = 0; q < 4; ++q)
#pragma unroll
        for (int k = 0; k < 8; ++k) sacc[q][k] = 0.0f;

    float vreg[4][8];
    if (!FIRST) {
#pragma unroll
        for (int q = 0; q < 4; ++q) {
            const float4* vp = (const float4*)(vsumg + ((((b0 + q) << 5) + c) << 4) + (dh << 3));
            float4 a0 = vp[0], a1 = vp[1];
            vreg[q][0] = a0.x; vreg[q][1] = a0.y; vreg[q][2] = a0.z; vreg[q][3] = a0.w;
            vreg[q][4] = a1.x; vreg[q][5] = a1.y; vreg[q][6] = a1.z; vreg[q][7] = a1.w;
        }
    }

    // staging: wave w stages tile-local bytes [w*2048, w*2048+2048)
    // LDS[L] = W[L ^ ((L>>10 & 7)<<4)]  -> pre-swizzle the *global* source.
    const int Dloc0 = (w << 11);
    const int lx0 = (lane << 4) ^ ((((w << 1)    ) & 7) << 4);
    const int lx1 = (lane << 4) ^ ((((w << 1) | 1) & 7) << 4);

    // x rows for this wave are uniform -> scalar loads
    const int wu = __builtin_amdgcn_readfirstlane(w);
    const float* xw = x + (size_t)((wu << 2) * R_ + r0) * 16;

#define STAGE(buf, r)                                                              \
    do {                                                                           \
        const char* wr_ = (const char*)W + ((size_t)(r) << 15);                    \
        gload_lds16(wr_ + Dloc0        + lx0, (char*)wlds[buf] + Dloc0);           \
        gload_lds16(wr_ + Dloc0 + 1024 + lx1, (char*)wlds[buf] + Dloc0 + 1024);    \
    } while (0)

    STAGE(0, r0);

#pragma unroll 1
    for (int t = 0; t < RB; ++t) {
        const int cur = t & 1;
        if (t + 1 < RB) {
            STAGE(cur ^ 1, r0 + t + 1);
            asm volatile("s_waitcnt vmcnt(2)" ::: "memory");
        } else {
            asm volatile("s_waitcnt vmcnt(0)" ::: "memory");
        }
        __builtin_amdgcn_s_barrier();
        __builtin_amdgcn_sched_barrier(0);

        const char* lb = (const char*)wlds[cur];
        float u[4][8];
#pragma unroll
        for (int q = 0; q < 4; ++q)
#pragma unroll
            for (int k = 0; k < 8; ++k) u[q][k] = 0.0f;

#pragma unroll
        for (int i = 0; i < 16; ++i) {
            const int A = (cb + (i << 6)) ^ key;
            float4 w0 = *(const float4*)(lb + A);
            float4 w1 = *(const float4*)(lb + (A ^ 16));
            float wv[8] = {w0.x, w0.y, w0.z, w0.w, w1.x, w1.y, w1.z, w1.w};
#pragma unroll
            for (int q = 0; q < 4; ++q) {
                const float xv = xw[(size_t)q * (R_ * 16) + t * 16 + i];
#pragma unroll
                for (int k = 0; k < 8; ++k)
                    u[q][k] = fmaf(xv, wv[k], u[q][k]);
            }
        }

#pragma unroll
        for (int q = 0; q < 4; ++q) {
            float cij;
            if (FIRST) {
                cij = 0.03125f;
            } else {
                float th = 0.0f;
#pragma unroll
                for (int k = 0; k < 8; ++k) th = fmaf(u[q][k], vreg[q][k], th);
                th += __shfl_xor(th, 32);          // fold the two d-halves
                float m = th;
#pragma unroll
                for (int off = 16; off >= 1; off >>= 1)
                    m = fmaxf(m, __shfl_xor(m, off));
                const float e = __expf(th - m);
                float ssum = e;
#pragma unroll
                for (int off = 16; off >= 1; off >>= 1)
                    ssum += __shfl_xor(ssum, off);
                cij = e / ssum;
            }
#pragma unroll
            for (int k = 0; k < 8; ++k)
                sacc[q][k] = fmaf(cij, u[q][k], sacc[q][k]);
        }

        __builtin_amdgcn_s_barrier();
    }
#undef STAGE

    if (ATOMIC) {
#pragma unroll
        for (int q = 0; q < 4; ++q) {
            float* sp = sdst + ((((b0 + q) << 5) + c) << 4) + (dh << 3);
#pragma unroll
            for (int k = 0; k < 8; ++k) atomicAdd(sp + k, sacc[q][k]);
        }
    } else {
#pragma unroll
        for (int q = 0; q < 4; ++q) {
            float* sp = sdst + ((size_t)blockIdx.x << 15) + ((((b0 + q) << 5) + c) << 4) + (dh << 3);
            ((float4*)sp)[0] = make_float4(sacc[q][0], sacc[q][1], sacc[q][2], sacc[q][3]);
            ((float4*)sp)[1] = make_float4(sacc[q][4], sacc[q][5], sacc[q][6], sacc[q][7]);
        }
    }
}

// stage-1 tree reduce: grid (128, 8) x 256. Block (e-chunk, pg) sums partials
// p in [pg*32, pg*32+32) for 256 consecutive elements -> s2[pg][e].
__global__ __launch_bounds__(256)
void caps_reduce1(const float* __restrict__ sp, float* __restrict__ s2)
{
    const int e  = blockIdx.x * 256 + threadIdx.x;   // 0..32767
    const int pg = blockIdx.y;
    const float* p0 = sp + (size_t)pg * 32 * SELEM + e;
    float a = 0.0f;
#pragma unroll 8
    for (int p = 0; p < 32; ++p) a += p0[(size_t)p * SELEM];
    s2[pg * SELEM + e] = a;
}

// stage-2 reduce + squash. mode 0: vsum = v; 1: vsum += v; 2: out = v.
__global__ __launch_bounds__(256)
void caps_reduce2(const float* __restrict__ src, int P,
                  float* __restrict__ vsum, float* __restrict__ out, int mode)
{
    const int e = blockIdx.x * 256 + threadIdx.x;    // 0..32767
    float a = 0.0f;
    for (int p = 0; p < P; ++p) a += src[(size_t)p * SELEM + e];
    float sq = a * a;
#pragma unroll
    for (int off = 8; off >= 1; off >>= 1) sq += __shfl_xor(sq, off);
    const float n = sqrtf(sq);
    const float v = a * (sq / (1.0f + sq) / (n + 1e-8f));
    if (mode == 0)      vsum[e] = v;
    else if (mode == 1) vsum[e] += v;
    else                out[e] = v;
}

extern "C" void kernel_launch(void* const* d_in, const int* in_sizes, int n_in,
                              void* d_out, int out_size, void* d_ws, size_t ws_size,
                              hipStream_t stream)
{
    const float* x = (const float*)d_in[0];          // [64, 4608, 16]
    const float* W = (const float*)d_in[1];          // [4608, 32, 16, 16]
    float* out = (float*)d_out;                      // [64, 32, 16]

    const size_t PART_BYTES = (size_t)(NBLK + 8 + 1) * SELEM * sizeof(float); // ~33.1 MiB
    if (ws_size >= PART_BYTES) {
        float* s_part = (float*)d_ws;                // [256][32768]
        float* s2     = s_part + (size_t)NBLK * SELEM;  // [8][32768]
        float* vsum   = s2 + (size_t)8 * SELEM;         // [32768]

        caps_pass<true, false><<<NBLK, 1024, 0, stream>>>(x, W, nullptr, s_part);
        caps_reduce1<<<dim3(128, 8), 256, 0, stream>>>(s_part, s2);
        caps_reduce2<<<128, 256, 0, stream>>>(s2, 8, vsum, nullptr, 0);

        caps_pass<false, false><<<NBLK, 1024, 0, stream>>>(x, W, vsum, s_part);
        caps_reduce1<<<dim3(128, 8), 256, 0, stream>>>(s_part, s2);
        caps_reduce2<<<128, 256, 0, stream>>>(s2, 8, vsum, nullptr, 1);

        caps_pass<false, false><<<NBLK, 1024, 0, stream>>>(x, W, vsum, s_part);
        caps_reduce1<<<dim3(128, 8), 256, 0, stream>>>(s_part, s2);
        caps_reduce2<<<128, 256, 0, stream>>>(s2, 8, nullptr, out, 2);
    } else {
        // fallback: atomic accumulation (order nondeterministic but well within
        // the validation threshold)
        float* s    = (float*)d_ws;                  // [32768]
        float* vsum = s + SELEM;                     // [32768]

        hipMemsetAsync(s, 0, SELEM * sizeof(float), stream);
        caps_pass<true, true><<<NBLK, 1024, 0, stream>>>(x, W, nullptr, s);
        caps_reduce2<<<128, 256, 0, stream>>>(s, 1, vsum, nullptr, 0);

        hipMemsetAsync(s, 0, SELEM * sizeof(float), stream);
        caps_pass<false, true><<<NBLK, 1024, 0, stream>>>(x, W, vsum, s);
        caps_reduce2<<<128, 256, 0, stream>>>(s, 1, vsum, nullptr, 1);

        hipMemsetAsync(s, 0, SELEM * sizeof(float), stream);
        caps_pass<false, true><<<NBLK, 1024, 0, stream>>>(x, W, vsum, s);
        caps_reduce2<<<128, 256, 0, stream>>>(s, 1, nullptr, out, 2);
    }
}